// Round 10
// baseline (281.889 us; speedup 1.0000x reference)
//
#include <hip/hip_runtime.h>

#define BATCH 4
#define CIN 64
#define HH 352
#define WW 1216
#define OCH 8
#define OHH 354
#define OWW 1218
#define HW (HH * WW)

#define PX 4        // cols per thread
#define TY 2        // rows per thread
#define TILE_W 64   // 16 tx * 4
#define TILE_H 16   // 8 ty * 2
#define NTHR 128
#define NW (CIN * 9 * OCH)   // 4608 folded weights

// Repack weights with BN folded in: w2[c*72 + (dh*3+dw)*8 + oc] = conv_w[oc][c][dh][dw] * scl[oc]
// bias at w2[4608 + oc] = beta - mean*scl
__global__ void repack_kernel(const float* __restrict__ conv_w,
                              const float* __restrict__ gamma,
                              const float* __restrict__ beta,
                              const float* __restrict__ mean,
                              const float* __restrict__ var,
                              float* __restrict__ w2)
{
    int tid = blockIdx.x * 256 + threadIdx.x;
    if (tid < NW) {
        int ct = tid >> 3;   // c*9 + tap
        int oc = tid & 7;
        float scl = gamma[oc] * rsqrtf(var[oc] + 1e-5f);
        w2[tid] = conv_w[oc * (CIN * 9) + ct] * scl;
    }
    if (tid < OCH) {
        float scl = gamma[tid] * rsqrtf(var[tid] + 1e-5f);
        w2[NW + tid] = beta[tid] - mean[tid] * scl;
    }
}

// Zero only the uncovered border of each (b,t) plane instead of 62 MB memset.
__global__ void border_kernel(float* __restrict__ out)
{
    const int bt = blockIdx.x;          // 0..35
    const int t = bt % 9;
    const int i = t / 3, j = t % 3;
    float* pl = out + (size_t)bt * OHH * OWW;
    const int r0 = (i == 0) ? HH : 0;
    const int r1 = (i == 2) ? 1 : (OHH - 1);
    const int c0 = (j == 0) ? WW : 0;
    const int c1 = (j == 2) ? 1 : (OWW - 1);
    const int nrow = 2 * OWW;
    for (int idx = threadIdx.x; idx < 2 * OWW + 2 * OHH; idx += blockDim.x) {
        if (idx < nrow) {
            int r = (idx < OWW) ? r0 : r1;
            int c = (idx < OWW) ? idx : idx - OWW;
            pl[(size_t)r * OWW + c] = 0.f;
        } else {
            int k = idx - nrow;
            int c = (k < OHH) ? c0 : c1;
            int r = (k < OHH) ? k : k - OHH;
            pl[(size_t)r * OWW + c] = 0.f;
        }
    }
}

__global__ __launch_bounds__(NTHR, 2)
void conv_kernel(const float* __restrict__ feature,
                 const float* __restrict__ w2all,
                 float* __restrict__ out)
{
    // Folded weights staged in LDS once: per-channel reads become pipelined
    // ds_read broadcasts instead of sL1-thrashing s_load L2 round-trips
    // (w2 is 18.4 KB > ~16 KB scalar L1 -> every channel iter re-missed).
    __shared__ __align__(16) float sw[NW];
    for (int i = threadIdx.x; i < NW; i += NTHR) sw[i] = w2all[i];
    __syncthreads();   // only barrier in the kernel

    const int tid = threadIdx.x;
    const int tx = tid & 15, ty = tid >> 4;     // 16 x 8
    const int b  = blockIdx.z;
    const int h0 = blockIdx.y * TILE_H + ty * TY;
    const int w0 = blockIdx.x * TILE_W + tx * PX;

    const int   cl  = max(w0 - 1, 0);
    const int   cr  = min(w0 + 4, WW - 1);
    const float mvl = (w0 >= 1) ? 1.f : 0.f;
    const float mvr = (w0 + 4 < WW) ? 1.f : 0.f;

    int offc[4], offl[4], offr[4];
    float rowm[4], mls[4], mrs[4];
#pragma unroll
    for (int r = 0; r < 4; ++r) {
        int gh = h0 - 1 + r;
        bool rok = (unsigned)gh < (unsigned)HH;
        int sgh = min(max(gh, 0), HH - 1);
        offc[r] = sgh * WW + w0;
        offl[r] = sgh * WW + cl;
        offr[r] = sgh * WW + cr;
        rowm[r] = rok ? 1.f : 0.f;
        mls[r]  = rowm[r] * mvl;
        mrs[r]  = rowm[r] * mvr;
    }

    const float* fp = feature + (size_t)b * CIN * HW;

    float acc[TY][PX][OCH];
#pragma unroll
    for (int oy = 0; oy < TY; ++oy)
#pragma unroll
        for (int p = 0; p < PX; ++p)
#pragma unroll
            for (int o = 0; o < OCH; ++o) acc[oy][p][o] = 0.f;

#pragma unroll 1
    for (int c = 0; c < CIN; ++c) {
        const float* cb = fp + (size_t)c * HW;
        // 12 independent loads, issued together
        float4 m0 = *(const float4*)(cb + offc[0]);
        float4 m1 = *(const float4*)(cb + offc[1]);
        float4 m2 = *(const float4*)(cb + offc[2]);
        float4 m3 = *(const float4*)(cb + offc[3]);
        float l0 = cb[offl[0]], l1 = cb[offl[1]], l2 = cb[offl[2]], l3 = cb[offl[3]];
        float r0 = cb[offr[0]], r1 = cb[offr[1]], r2 = cb[offr[2]], r3 = cb[offr[3]];

        float f[4][6];
        f[0][0] = l0 * mls[0]; f[0][1] = m0.x * rowm[0]; f[0][2] = m0.y * rowm[0];
        f[0][3] = m0.z * rowm[0]; f[0][4] = m0.w * rowm[0]; f[0][5] = r0 * mrs[0];
        f[1][0] = l1 * mls[1]; f[1][1] = m1.x * rowm[1]; f[1][2] = m1.y * rowm[1];
        f[1][3] = m1.z * rowm[1]; f[1][4] = m1.w * rowm[1]; f[1][5] = r1 * mrs[1];
        f[2][0] = l2 * mls[2]; f[2][1] = m2.x * rowm[2]; f[2][2] = m2.y * rowm[2];
        f[2][3] = m2.z * rowm[2]; f[2][4] = m2.w * rowm[2]; f[2][5] = r2 * mrs[2];
        f[3][0] = l3 * mls[3]; f[3][1] = m3.x * rowm[3]; f[3][2] = m3.y * rowm[3];
        f[3][3] = m3.z * rowm[3]; f[3][4] = m3.w * rowm[3]; f[3][5] = r3 * mrs[3];

        const float* wc = &sw[c * 72];   // LDS, uniform addr -> broadcast ds_read
#pragma unroll
        for (int dh = 0; dh < 3; ++dh)
#pragma unroll
            for (int dw = 0; dw < 3; ++dw)
#pragma unroll
                for (int o = 0; o < OCH; ++o) {
                    float wv = wc[(dh * 3 + dw) * OCH + o];
#pragma unroll
                    for (int oy = 0; oy < TY; ++oy)
#pragma unroll
                        for (int p = 0; p < PX; ++p)
                            acc[oy][p][o] = fmaf(f[oy + dh][p + dw], wv, acc[oy][p][o]);
                }
    }

    // Epilogue: bias, L1-normalize, mid, scatter 9 shifted planes.
    const float* bb = w2all + NW;
    float sb[OCH];
#pragma unroll
    for (int o = 0; o < OCH; ++o) sb[o] = bb[o];

    float* ob = out + (size_t)b * 9 * OHH * OWW;
#pragma unroll
    for (int oy = 0; oy < TY; ++oy) {
        const int h = h0 + oy;
#pragma unroll
        for (int p = 0; p < PX; ++p) {
            const int w = w0 + p;
            float g[OCH];
            float asum = 0.f;
#pragma unroll
            for (int o = 0; o < OCH; ++o) {
                float v = acc[oy][p][o] + sb[o];
                g[o] = v;
                asum += fabsf(v);
            }
            float inv = 1.0f / asum;
            float ss = 0.f;
#pragma unroll
            for (int o = 0; o < OCH; ++o) { g[o] *= inv; ss += g[o]; }
            float mid = 1.0f - ss;
#pragma unroll
            for (int t = 0; t < 9; ++t) {
                int i = t / 3, j = t - i * 3;
                float v = (t < 4) ? g[t] : ((t == 4) ? mid : g[t - 1]);
                ob[((size_t)t * OHH + (h + i)) * OWW + (w + j)] = v;
            }
        }
    }
}

extern "C" void kernel_launch(void* const* d_in, const int* in_sizes, int n_in,
                              void* d_out, int out_size, void* d_ws, size_t ws_size,
                              hipStream_t stream) {
    const float* feature = (const float*)d_in[0];
    const float* conv_w  = (const float*)d_in[1];
    const float* gamma   = (const float*)d_in[2];
    const float* beta    = (const float*)d_in[3];
    const float* mean    = (const float*)d_in[4];
    const float* var     = (const float*)d_in[5];
    float* out = (float*)d_out;
    float* w2  = (float*)d_ws;   // 4608 + 8 floats

    border_kernel<<<BATCH * 9, 256, 0, stream>>>(out);
    repack_kernel<<<(NW + 255) / 256, 256, 0, stream>>>(
        conv_w, gamma, beta, mean, var, w2);

    dim3 grid(WW / TILE_W, HH / TILE_H, BATCH);  // 19 x 22 x 4
    conv_kernel<<<grid, NTHR, 0, stream>>>(feature, w2, out);
}

// Round 11
// 251.813 us; speedup vs baseline: 1.1194x; 1.1194x over previous
//
#include <hip/hip_runtime.h>
#include <hip/hip_bf16.h>

#define BATCH 4
#define CIN 64
#define HH 352
#define WW 1216
#define OCH 8
#define OHH 354
#define OWW 1218
#define HW (HH * WW)

#define BH 16       // output rows per block
#define BW 32       // output cols per block
#define FR 18       // staged feature rows (halo)
#define FC 34       // staged feature cols (halo)
#define NPOS (FR * FC)   // 612 positions
#define NTHR 256

typedef short bf16x8 __attribute__((ext_vector_type(8)));
typedef float f32x4  __attribute__((ext_vector_type(4)));

// fp32 -> bf16 round-to-nearest-even (branchless, finite inputs)
static __device__ __forceinline__ unsigned f2bf(float x) {
    unsigned u = __float_as_uint(x);
    return (u + 0x7FFFu + ((u >> 16) & 1u)) >> 16;
}

// Bake weights into exact MFMA B-fragment layout (bf16, BN-folded, oc>=8 zero):
// wB[(tap*2+cc)*64 + lane] = 8 bf16: B[k = hi*8+j][col = oc], k-channel = cc*32+hi*8+j
__global__ void repack_kernel(const float* __restrict__ conv_w,
                              const float* __restrict__ gamma,
                              const float* __restrict__ beta,
                              const float* __restrict__ mean,
                              const float* __restrict__ var,
                              unsigned short* __restrict__ wB,
                              float* __restrict__ bias)
{
    int tid = blockIdx.x * 256 + threadIdx.x;
    if (tid < 18 * 64) {
        int tc = tid >> 6;          // tap*2 + cc
        int lane = tid & 63;
        int tap = tc >> 1, cc = tc & 1;
        int oc = lane & 15, hi = lane >> 4;
        unsigned v[8];
#pragma unroll
        for (int j = 0; j < 8; ++j) {
            float w = 0.f;
            if (oc < 8) {
                int c = cc * 32 + hi * 8 + j;
                float scl = gamma[oc] * rsqrtf(var[oc] + 1e-5f);
                w = conv_w[((size_t)oc * CIN + c) * 9 + tap] * scl;
            }
            v[j] = f2bf(w);
        }
        uint4 pk;
        pk.x = v[0] | (v[1] << 16);
        pk.y = v[2] | (v[3] << 16);
        pk.z = v[4] | (v[5] << 16);
        pk.w = v[6] | (v[7] << 16);
        ((uint4*)wB)[tid] = pk;
    }
    if (tid < OCH) {
        float scl = gamma[tid] * rsqrtf(var[tid] + 1e-5f);
        bias[tid] = beta[tid] - mean[tid] * scl;
    }
}

// Zero only the uncovered border ring of each (b,t) plane.
__global__ void border_kernel(float* __restrict__ out)
{
    const int bt = blockIdx.x;          // 0..35
    const int t = bt % 9;
    const int i = t / 3, j = t % 3;
    float* pl = out + (size_t)bt * OHH * OWW;
    const int r0 = (i == 0) ? HH : 0;
    const int r1 = (i == 2) ? 1 : (OHH - 1);
    const int c0 = (j == 0) ? WW : 0;
    const int c1 = (j == 2) ? 1 : (OWW - 1);
    const int nrow = 2 * OWW;
    for (int idx = threadIdx.x; idx < 2 * OWW + 2 * OHH; idx += blockDim.x) {
        if (idx < nrow) {
            int r = (idx < OWW) ? r0 : r1;
            int c = (idx < OWW) ? idx : idx - OWW;
            pl[(size_t)r * OWW + c] = 0.f;
        } else {
            int k = idx - nrow;
            int c = (k < OHH) ? c0 : c1;
            int r = (k < OHH) ? k : k - OHH;
            pl[(size_t)r * OWW + c] = 0.f;
        }
    }
}

__global__ __launch_bounds__(NTHR, 2)
void conv_mfma(const float* __restrict__ feature,
               const unsigned short* __restrict__ wB,
               const float* __restrict__ bias,
               float* __restrict__ out)
{
    // LDS feature tile: [fr][fc][ch-chunk of 32] bf16, ch innermost -> A-frag is one b128
    __shared__ uint4 sF[NPOS * 4];      // 612*4*16B = 39168 B

    const int tid  = threadIdx.x;
    const int wave = tid >> 6;
    const int lane = tid & 63;
    const int oc   = lane & 15;         // B col / C col; also A pixel-row index
    const int hi   = lane >> 4;         // k-octet / C row-quarter
    const int b  = blockIdx.z;
    const int h0 = blockIdx.y * BH;
    const int w0 = blockIdx.x * BW;

    const float* fb = feature + (size_t)b * CIN * HW;

    f32x4 acc[4][2];
#pragma unroll
    for (int rr = 0; rr < 4; ++rr)
#pragma unroll
        for (int cg = 0; cg < 2; ++cg) acc[rr][cg] = (f32x4)0.f;

#pragma unroll 1
    for (int cc = 0; cc < 2; ++cc) {
        if (cc) __syncthreads();        // all reads of chunk 0 done before overwrite
        // ---- stage 32 channels of the 18x34 halo tile, fp32 -> bf16 ----
#pragma unroll 1
        for (int it = 0; it < 10; ++it) {
            int task = it * NTHR + tid;           // < 612*4
            if (task < NPOS * 4) {
                int pos = task >> 2;
                int oct = task & 3;
                int fr = pos / FC;
                int fc = pos - fr * FC;
                int gh = h0 - 1 + fr, gw = w0 - 1 + fc;
                bool ok = ((unsigned)gh < (unsigned)HH) && ((unsigned)gw < (unsigned)WW);
                float v[8];
#pragma unroll
                for (int j = 0; j < 8; ++j) v[j] = 0.f;
                if (ok) {
                    const float* sp = fb + (size_t)(cc * 32 + oct * 8) * HW + gh * WW + gw;
#pragma unroll
                    for (int j = 0; j < 8; ++j) v[j] = sp[(size_t)j * HW];
                }
                uint4 pk;
                pk.x = f2bf(v[0]) | (f2bf(v[1]) << 16);
                pk.y = f2bf(v[2]) | (f2bf(v[3]) << 16);
                pk.z = f2bf(v[4]) | (f2bf(v[5]) << 16);
                pk.w = f2bf(v[6]) | (f2bf(v[7]) << 16);
                sF[pos * 4 + oct] = pk;
            }
        }
        // B-fragments for this chunk: 9 taps x 16B per lane (coalesced)
        bf16x8 bw[9];
#pragma unroll
        for (int t = 0; t < 9; ++t)
            bw[t] = ((const bf16x8*)wB)[(t * 2 + cc) * 64 + lane];
        __syncthreads();
        // ---- 72 MFMAs: 9 taps x (4 rows x 2 colgroups) ----
#pragma unroll
        for (int t = 0; t < 9; ++t) {
            const int dh = t / 3, dw = t % 3;
#pragma unroll
            for (int rr = 0; rr < 4; ++rr) {
                const int fr = wave * 4 + rr + dh;
#pragma unroll
                for (int cg = 0; cg < 2; ++cg) {
                    const int fc = cg * 16 + oc + dw;
                    bf16x8 av = *reinterpret_cast<const bf16x8*>(&sF[(fr * FC + fc) * 4 + hi]);
                    acc[rr][cg] = __builtin_amdgcn_mfma_f32_16x16x32_bf16(av, bw[t], acc[rr][cg], 0, 0, 0);
                }
            }
        }
    }

    // ---- epilogue: bias, L1-normalize across oc (16-lane shfl reduce), mid, scatter ----
    const float myb = (oc < 8) ? bias[oc] : 0.f;
    const int t = (oc < 8) ? ((oc < 4) ? oc : oc + 1) : 4;
    const bool dow = (oc <= 8);
    const int ii = t / 3, jj = t % 3;
    float* pl = out + ((size_t)(b * 9 + t) * OHH + ii) * OWW + jj;

#pragma unroll
    for (int rr = 0; rr < 4; ++rr) {
        const int h = h0 + wave * 4 + rr;
#pragma unroll
        for (int cg = 0; cg < 2; ++cg) {
#pragma unroll
            for (int reg = 0; reg < 4; ++reg) {
                float v = acc[rr][cg][reg] + myb;   // lanes oc>=8: 0
                float av = fabsf(v);
                float sv = v;
                av += __shfl_xor(av, 1);  sv += __shfl_xor(sv, 1);
                av += __shfl_xor(av, 2);  sv += __shfl_xor(sv, 2);
                av += __shfl_xor(av, 4);  sv += __shfl_xor(sv, 4);
                av += __shfl_xor(av, 8);  sv += __shfl_xor(sv, 8);
                float inv = 1.0f / av;
                float val = (oc == 8) ? (1.0f - sv * inv) : (v * inv);
                if (dow) {
                    int w = w0 + cg * 16 + hi * 4 + reg;
                    pl[(size_t)h * OWW + w] = val;
                }
            }
        }
    }
}

extern "C" void kernel_launch(void* const* d_in, const int* in_sizes, int n_in,
                              void* d_out, int out_size, void* d_ws, size_t ws_size,
                              hipStream_t stream) {
    const float* feature = (const float*)d_in[0];
    const float* conv_w  = (const float*)d_in[1];
    const float* gamma   = (const float*)d_in[2];
    const float* beta    = (const float*)d_in[3];
    const float* mean    = (const float*)d_in[4];
    const float* var     = (const float*)d_in[5];
    float* out = (float*)d_out;
    unsigned short* wB = (unsigned short*)d_ws;            // 18432 B of bf16 B-frags
    float* bias = (float*)((char*)d_ws + 18432);           // 8 floats

    border_kernel<<<BATCH * 9, 256, 0, stream>>>(out);
    repack_kernel<<<5, 256, 0, stream>>>(conv_w, gamma, beta, mean, var, wB, bias);

    dim3 grid(WW / BW, HH / BH, BATCH);   // 38 x 22 x 4
    conv_mfma<<<grid, NTHR, 0, stream>>>(feature, wB, bias, out);
}